// Round 1
// baseline (302.801 us; speedup 1.0000x reference)
//
#include <hip/hip_runtime.h>
#include <hip/hip_bf16.h>

// IWHT3Layer: 3 branches of (per-coeff matmul [16,12544,64]x[16,64,64]) +
// inverse 2D 4x4 WHT over the 16 coefficients + bias.
// Inputs: float32. Output: float32.
//
// R5 change vs R4 (302us bench / 110us iwht dispatch, occupancy 26%):
// Occupancy was register-bound: 76 VGPR + 64 AGPR acc = 140 unified regs ->
// rounds to 192-granule -> 2 waves/SIMD (2 blocks/CU), matching the measured
// 26%. Fix:
//  (a) Swap MFMA operands (A=weights, B=x) -> C^T: each thread now holds 4
//      CONSECUTIVE k for ONE site. Epilogue: 1 obase instead of 4 (saves ~8
//      VGPRs), float4 bias, and 16 dwordx4 stores instead of 64 scalar stores.
//      A/B fragments have identical lane layouts (both already verified in
//      this kernel), so the swap only changes argument order + epilogue.
//  (b) __launch_bounds__(256, 4): cap at 128 regs/wave -> 4 waves/SIMD ->
//      4 blocks/CU (LDS 4x34816 = 139KB fits in 160KB).
// Staging (global_load_lds DMA, 4-t chunks double-buffered, 272B padded rows)
// identical to the verified R4 kernel.

typedef __attribute__((ext_vector_type(8))) short bf16x8;   // 8 bf16 (4 VGPRs)
typedef __attribute__((ext_vector_type(4))) float floatx4;  // MFMA C/D

#define NSITES 12544
#define NTILES 784
#define OUT_PER_BRANCH 12845056  // 16*112*112*64
#define WT_ELEMS (3*16*64*64)
#define ROW_F 68                 // LDS row stride in floats: 64 data + 4 pad
#define CHUNK_F (64 * ROW_F)     // 4 t * 16 rows = 64 rows per chunk (17408 B)

__device__ __forceinline__ short f32_to_bf16_bits(float f) {
    __hip_bfloat16 h = __float2bfloat16(f);  // RNE
    return *reinterpret_cast<short*>(&h);
}

__global__ void transpose_weights(const float* __restrict__ w0,
                                  const float* __restrict__ w1,
                                  const float* __restrict__ w2,
                                  __hip_bfloat16* __restrict__ wT) {
    int idx = blockIdx.x * blockDim.x + threadIdx.x;  // [0, 3*16*64*64)
    if (idx >= WT_ELEMS) return;
    int c  = idx & 63;
    int k  = (idx >> 6) & 63;
    int t  = (idx >> 12) & 15;
    int br = idx >> 16;
    const float* w = (br == 0) ? w0 : ((br == 1) ? w1 : w2);
    // wT[br][t][k][c] = bf16(w[br][t][c][k])
    wT[idx] = __float2bfloat16(w[(t * 64 + c) * 64 + k]);
}

template <bool USE_WT>
__global__ __launch_bounds__(256, 4) void iwht_kernel(
    const float* __restrict__ x0, const float* __restrict__ x1,
    const float* __restrict__ x2,
    const float* __restrict__ w0, const float* __restrict__ w1,
    const float* __restrict__ w2,
    const __hip_bfloat16* __restrict__ wT,
    const float* __restrict__ b0, const float* __restrict__ b1,
    const float* __restrict__ b2,
    float* __restrict__ out) {
    __shared__ float xs[2][CHUNK_F];  // 2 x 17408 B = 34816 B

    int bx   = blockIdx.x;
    int br   = bx / NTILES;
    int tile = bx - br * NTILES;
    int lane = threadIdx.x & 63;
    int wave = threadIdx.x >> 6;
    int l15  = lane & 15;
    int quad = lane >> 4;
    int n    = wave * 16 + l15;  // weight-fragment row: output channel block

    const float* x    = (br == 0) ? x0 : ((br == 1) ? x1 : x2);
    const float* w    = (br == 0) ? w0 : ((br == 1) ? w1 : w2);
    const float* bias = (br == 0) ? b0 : ((br == 1) ? b1 : b2);

    // DMA source base: row (t, s) starts at x + (t*NSITES + tile*16 + s)*64;
    // lane contributes 4 bytes at +lane.
    const float* xg = x + (size_t)(tile * 16) * 64 + lane;

    floatx4 acc[16];
#pragma unroll
    for (int t = 0; t < 16; t++) acc[t] = (floatx4){0.f, 0.f, 0.f, 0.f};

    // --- stage chunk g (t = 4g..4g+3) into xs[buf]: wave handles 16 rows ---
#define STAGE(g, buf)                                                          \
    {                                                                          \
        _Pragma("unroll") for (int r = 0; r < 16; r++) {                       \
            int row = wave * 16 + r; /* row = tl*16 + s */                     \
            int tl  = row >> 4;                                                \
            int s   = row & 15;                                                \
            const float* gp = xg + ((size_t)((g) * 4 + tl) * NSITES + s) * 64; \
            __builtin_amdgcn_global_load_lds(                                  \
                (const __attribute__((address_space(1))) void*)gp,             \
                (__attribute__((address_space(3))) void*)&xs[buf][row * ROW_F],\
                4, 0, 0);                                                      \
        }                                                                      \
    }

    STAGE(0, 0);
    __syncthreads();

#pragma unroll
    for (int g = 0; g < 4; g++) {
        int buf = g & 1;
        if (g < 3) STAGE(g + 1, buf ^ 1);
#pragma unroll
        for (int tl = 0; tl < 4; tl++) {
            int t = g * 4 + tl;
            // x fragment (now the MFMA *B* operand): xs row (tl*16 + l15),
            // c = quad*8..+7 and +32 (f32, 16B aligned)
            const float* rowp = &xs[buf][(tl * 16 + l15) * ROW_F + quad * 8];
            floatx4 f0 = ((const floatx4*)rowp)[0];
            floatx4 f1 = ((const floatx4*)rowp)[1];
            floatx4 f2 = ((const floatx4*)(rowp + 32))[0];
            floatx4 f3 = ((const floatx4*)(rowp + 32))[1];
            bf16x8 a0, a1;
#pragma unroll
            for (int j = 0; j < 4; j++) {
                a0[j]     = f32_to_bf16_bits(f0[j]);
                a0[j + 4] = f32_to_bf16_bits(f1[j]);
                a1[j]     = f32_to_bf16_bits(f2[j]);
                a1[j + 4] = f32_to_bf16_bits(f3[j]);
            }
            bf16x8 bb0, bb1;
            if (USE_WT) {
                // weight fragment (now the MFMA *A* operand):
                // wT[br][t][n][c] bf16, same c<->lane mapping as x fragment
                const bf16x8* wv = reinterpret_cast<const bf16x8*>(
                    wT + (((size_t)(br * 16 + t) * 64 + n) * 64) + quad * 8);
                bb0 = wv[0];
                bb1 = wv[4];  // +32 c elements
            } else {
                // fallback: strided f32 loads from original w[t][c][k]
#pragma unroll
                for (int j = 0; j < 8; j++) {
                    int c0 = quad * 8 + j;
                    bb0[j] = f32_to_bf16_bits(w[(t * 64 + c0) * 64 + n]);
                    bb1[j] = f32_to_bf16_bits(w[(t * 64 + c0 + 32) * 64 + n]);
                }
            }
            // Swapped operands vs R4: D = W * X -> D[row=k, col=site].
            // Thread (wave,quad,l15,reg) holds y[t][site=tile*16+l15]
            //                                     [k = wave*16 + quad*4 + reg]
            acc[t] = __builtin_amdgcn_mfma_f32_16x16x32_bf16(bb0, a0, acc[t], 0, 0, 0);
            acc[t] = __builtin_amdgcn_mfma_f32_16x16x32_bf16(bb1, a1, acc[t], 0, 0, 0);
        }
        if (g < 3) __syncthreads();
    }
#undef STAGE

    // Epilogue: one site per thread, 4 consecutive k per reg -> float4 stores.
    int k0   = wave * 16 + quad * 4;
    int site = tile * 16 + l15;
    int b    = site / 784;
    int rem  = site - b * 784;
    int i    = rem / 28;
    int j    = rem - i * 28;
    float* op = out + (size_t)br * OUT_PER_BRANCH +
                (((size_t)(b * 112 + 4 * i)) * 112 + 4 * j) * 64 + k0;
    floatx4 bias4 = *reinterpret_cast<const floatx4*>(bias + k0);

    // Inverse WHT over v (t = 4u+v): acc[4u+q] = sum_v H[q][v] y[4u+v]
#pragma unroll
    for (int u = 0; u < 4; u++) {
        floatx4 y0 = acc[4 * u + 0], y1 = acc[4 * u + 1];
        floatx4 y2 = acc[4 * u + 2], y3 = acc[4 * u + 3];
        floatx4 A = y0 + y2, Bv = y1 + y3, Cv = y0 - y2, Dv = y1 - y3;
        acc[4 * u + 0] = A + Bv;
        acc[4 * u + 1] = A - Bv;
        acc[4 * u + 2] = Cv + Dv;
        acc[4 * u + 3] = Cv - Dv;
    }

    // Inverse WHT over u, then scale + bias + vectorized store (dwordx4).
#pragma unroll
    for (int q = 0; q < 4; q++) {
        floatx4 z0 = acc[0 + q], z1 = acc[4 + q], z2 = acc[8 + q], z3 = acc[12 + q];
        floatx4 A = z0 + z2, Bv = z1 + z3, Cv = z0 - z2, Dv = z1 - z3;
        floatx4 o[4];
        o[0] = A + Bv;
        o[1] = A - Bv;
        o[2] = Cv + Dv;
        o[3] = Cv - Dv;
#pragma unroll
        for (int p = 0; p < 4; p++) {
            floatx4 v = o[p] * 0.0625f + bias4;
            *reinterpret_cast<floatx4*>(op + (size_t)(p * 112 + q) * 64) = v;
        }
    }
}

extern "C" void kernel_launch(void* const* d_in, const int* in_sizes, int n_in,
                              void* d_out, int out_size, void* d_ws, size_t ws_size,
                              hipStream_t stream) {
    const float* x0 = (const float*)d_in[0];
    const float* x1 = (const float*)d_in[1];
    const float* x2 = (const float*)d_in[2];
    const float* w0 = (const float*)d_in[3];
    const float* w1 = (const float*)d_in[4];
    const float* w2 = (const float*)d_in[5];
    const float* b0 = (const float*)d_in[6];
    const float* b1 = (const float*)d_in[7];
    const float* b2 = (const float*)d_in[8];
    float* out = (float*)d_out;
    __hip_bfloat16* wT = (__hip_bfloat16*)d_ws;

    bool use_wt = ws_size >= (size_t)WT_ELEMS * sizeof(__hip_bfloat16);
    if (use_wt) {
        transpose_weights<<<(WT_ELEMS + 255) / 256, 256, 0, stream>>>(w0, w1, w2, wT);
        iwht_kernel<true><<<3 * NTILES, 256, 0, stream>>>(x0, x1, x2, w0, w1, w2, wT,
                                                          b0, b1, b2, out);
    } else {
        iwht_kernel<false><<<3 * NTILES, 256, 0, stream>>>(x0, x1, x2, w0, w1, w2, wT,
                                                           b0, b1, b2, out);
    }
}